// Round 6
// baseline (835.100 us; speedup 1.0000x reference)
//
#include <hip/hip_runtime.h>

typedef unsigned int u32;
typedef unsigned short u16;

#define FLT_BIG 3.402823466e+38f
#define CPE 64          // chunks per event (chunk <= 8M/CPE if one event = all points is false here; 2M/64=31250 < 65536 -> u16-safe)
#define HWORDS 16000    // LDS u32 words = 32000 u16 counters (64 KB static)

// Order-preserving map: float -> u32 so unsigned atomicMin == float min.
__device__ __forceinline__ u32 f2ord(float f){
    u32 b = __float_as_uint(f);
    return (b & 0x80000000u) ? ~b : (b | 0x80000000u);
}
__device__ __forceinline__ float ord2f(u32 k){
    u32 b = (k & 0x80000000u) ? (k ^ 0x80000000u) : ~k;
    return __uint_as_float(b);
}

// NOTE: JAX x64 disabled -> "int64" inputs are int32 on device.
__global__ void k_init(u32* __restrict__ mins,
                       float* __restrict__ out_tail,
                       const int* __restrict__ nbins,
                       const float* __restrict__ bin_width,
                       int ndims){
    int t = threadIdx.x;
    if (t < 3) mins[t] = 0xFFFFFFFFu;
    if (t < ndims) out_tail[t] = (float)nbins[t];
    if (t == 0) out_tail[ndims] = bin_width[0];
}

// Per-dim min over [N,3] f32, read as groups of 3 float4 (= 4 points).
__global__ void k_min3(const float4* __restrict__ c4, int ngroups, u32* __restrict__ mins){
    float m0 = FLT_BIG, m1 = FLT_BIG, m2 = FLT_BIG;
    const int stride = gridDim.x * blockDim.x;
    for (int g = blockIdx.x * blockDim.x + threadIdx.x; g < ngroups; g += stride){
        const float4 v0 = c4[3*g+0];
        const float4 v1 = c4[3*g+1];
        const float4 v2 = c4[3*g+2];
        m0 = fminf(m0, fminf(v0.x, v0.w)); m1 = fminf(m1, v0.y); m2 = fminf(m2, v0.z);
        m1 = fminf(m1, fminf(v1.x, v1.w)); m2 = fminf(m2, v1.y); m0 = fminf(m0, v1.z);
        m2 = fminf(m2, fminf(v2.x, v2.w)); m0 = fminf(m0, v2.y); m1 = fminf(m1, v2.z);
    }
    #pragma unroll
    for (int off = 32; off > 0; off >>= 1){
        m0 = fminf(m0, __shfl_down(m0, off));
        m1 = fminf(m1, __shfl_down(m1, off));
        m2 = fminf(m2, __shfl_down(m2, off));
    }
    if ((threadIdx.x & 63) == 0){
        atomicMin(mins + 0, f2ord(m0));
        atomicMin(mins + 1, f2ord(m1));
        atomicMin(mins + 2, f2ord(m2));
    }
}

__device__ __forceinline__ int bin_of(float x, float mn, float w, int nb){
    float c = x - mn;
    int b = (int)floorf(c / w);
    b = b < 0 ? 0 : b;
    b = b > nb - 1 ? nb - 1 : b;
    return b;
}

__device__ __forceinline__ int row_of(int p, int sp0, int sp1, int sp2,
                                      const int* row_splits, int n_rs){
    int r = (p >= sp0) + (p >= sp1) + (p >= sp2);
    if (n_rs > 4){
        for (int k = 4; k < n_rs; ++k) r += (p >= row_splits[k]) ? 1 : 0;
    }
    return r;
}

// LDS-privatized histogram. One block per (event, chunk); the chunk lies
// entirely inside one event (row index constant per block -> spatial bins
// only). Two passes over the chunk: spatial < half, then >= half; second
// pass re-reads L2-warm data. Counters: u16 packed 2-per-u32, LDS atomics.
// chunk_len < 65536 guaranteed (host checks), so u16 cannot overflow.
__global__ __launch_bounds__(1024)
void k_hist_lds(const float* __restrict__ coords,
                const int* __restrict__ row_splits,
                const int* __restrict__ nbins,
                const float* __restrict__ bin_width,
                const u32* __restrict__ mins,
                u32* __restrict__ part,      // [n_rs*CPE][2][HWORDS] u32
                int spatial, int half){
    __shared__ u32 hh[HWORDS];

    const float w  = bin_width[0];
    const float mn0 = ord2f(mins[0]);
    const float mn1 = ord2f(mins[1]);
    const float mn2 = ord2f(mins[2]);
    const int nb1 = nbins[1], nb2 = nbins[2];

    const int e = blockIdx.x / CPE;
    const int i = blockIdx.x % CPE;
    const int lo = row_splits[e];
    const int hi = row_splits[e + 1];
    const long long len = (long long)hi - lo;
    const int start = lo + (int)((len * i) / CPE);
    const int end   = lo + (int)((len * (i + 1)) / CPE);

    int a4 = (start + 3) & ~3; if (a4 > end) a4 = end;
    int b4 = end & ~3;         if (b4 < a4) b4 = a4;
    const int tid = threadIdx.x;
    const float4* c4 = (const float4*)coords;

    for (int hp = 0; hp < 2; ++hp){
        for (int j = tid; j < HWORDS; j += 1024) hh[j] = 0;
        __syncthreads();
        const int F0 = hp ? half : 0;
        const int F1 = hp ? spatial : half;

        // scalar head + tail
        const int nh = a4 - start;
        const int nt = end - b4;
        if (tid < nh + nt){
            const int p = (tid < nh) ? (start + tid) : (b4 + (tid - nh));
            const int b0 = bin_of(coords[3LL*p+0], mn0, w, nbins[0]);
            const int b1 = bin_of(coords[3LL*p+1], mn1, w, nb1);
            const int b2 = bin_of(coords[3LL*p+2], mn2, w, nb2);
            const int s = (b0 * nb1 + b1) * nb2 + b2;
            if (s >= F0 && s < F1){
                const int idx = s - F0;
                atomicAdd(&hh[idx >> 1], 1u << ((idx & 1) << 4));
            }
        }
        // vector body
        const int nb0 = nbins[0];
        for (int g = (a4 >> 2) + tid; g < (b4 >> 2); g += 1024){
            const float4 v0 = c4[3*g+0];
            const float4 v1 = c4[3*g+1];
            const float4 v2 = c4[3*g+2];
            float px[4], py[4], pz[4];
            px[0]=v0.x; py[0]=v0.y; pz[0]=v0.z;
            px[1]=v0.w; py[1]=v1.x; pz[1]=v1.y;
            px[2]=v1.z; py[2]=v1.w; pz[2]=v2.x;
            px[3]=v2.y; py[3]=v2.z; pz[3]=v2.w;
            #pragma unroll
            for (int j = 0; j < 4; ++j){
                const int b0 = bin_of(px[j], mn0, w, nb0);
                const int b1 = bin_of(py[j], mn1, w, nb1);
                const int b2 = bin_of(pz[j], mn2, w, nb2);
                const int s = (b0 * nb1 + b1) * nb2 + b2;
                if (s >= F0 && s < F1){
                    const int idx = s - F0;
                    atomicAdd(&hh[idx >> 1], 1u << ((idx & 1) << 4));
                }
            }
        }
        __syncthreads();
        // flush partial (coalesced u32 stream)
        u32* dst = part + ((long long)(e * CPE + i) * 2 + hp) * HWORDS;
        for (int j = tid; j < HWORDS; j += 1024) dst[j] = hh[j];
        __syncthreads();   // protect hh before next pass's zeroing
    }
}

// counts_out[b] = (float) sum over CPE chunk-partials of b's event.
__global__ void k_hreduce(const u16* __restrict__ part, int total_bins,
                          int spatial, int half, float* __restrict__ counts_out){
    int b = blockIdx.x * blockDim.x + threadIdx.x;
    if (b >= total_bins) return;
    const int e = b / spatial;
    const int s = b % spatial;
    const int hp = (s >= half) ? 1 : 0;
    const int idx = s - hp * half;
    const u16* base = part + ((long long)(e * CPE) * 2 + hp) * (2 * HWORDS) + idx;
    int sum = 0;
    #pragma unroll 8
    for (int i = 0; i < CPE; ++i) sum += base[(long long)i * 2 * (2 * HWORDS)];
    counts_out[b] = (float)sum;
}

// Output pass: pure streaming, no atomics. Overwrites the partials scratch
// region (safe: k_hreduce already consumed it — stream-ordered).
__global__ void k_out(const float* __restrict__ coords,
                      const int* __restrict__ row_splits, int n_rs,
                      const int* __restrict__ nbins,
                      const float* __restrict__ bin_width,
                      const u32* __restrict__ mins,
                      int N,
                      float* __restrict__ out){
    const float w  = bin_width[0];
    const float mn0 = ord2f(mins[0]);
    const float mn1 = ord2f(mins[1]);
    const float mn2 = ord2f(mins[2]);
    const int nb0 = nbins[0], nb1 = nbins[1], nb2 = nbins[2];
    const int sp0 = (1 <= n_rs) ? row_splits[1] : 0x7FFFFFFF;
    const int sp1 = (2 <= n_rs) ? row_splits[2] : 0x7FFFFFFF;
    const int sp2 = (3 <= n_rs) ? row_splits[3] : 0x7FFFFFFF;

    float4* out_assigned = (float4*)out;                 // [N] x float4
    float*  out_flat     = out + 4LL * (long long)N;     // [N]
    const float4* c4 = (const float4*)coords;

    const int ngroups = N >> 2;
    const int stride = gridDim.x * blockDim.x;
    const int tid0 = blockIdx.x * blockDim.x + threadIdx.x;

    for (int g = tid0; g < ngroups; g += stride){
        const float4 v0 = c4[3*g+0];
        const float4 v1 = c4[3*g+1];
        const float4 v2 = c4[3*g+2];
        float px[4], py[4], pz[4];
        px[0]=v0.x; py[0]=v0.y; pz[0]=v0.z;
        px[1]=v0.w; py[1]=v1.x; pz[1]=v1.y;
        px[2]=v1.z; py[2]=v1.w; pz[2]=v2.x;
        px[3]=v2.y; py[3]=v2.z; pz[3]=v2.w;

        const int base = g << 2;
        float fl[4];
        #pragma unroll
        for (int j = 0; j < 4; ++j){
            const int p = base + j;
            const int r = row_of(p, sp0, sp1, sp2, row_splits, n_rs);
            const int b0 = bin_of(px[j], mn0, w, nb0);
            const int b1 = bin_of(py[j], mn1, w, nb1);
            const int b2 = bin_of(pz[j], mn2, w, nb2);
            out_assigned[p] = make_float4((float)r, (float)b0, (float)b1, (float)b2);
            const int flat = ((r * nb0 + b0) * nb1 + b1) * nb2 + b2;
            fl[j] = (float)flat;
        }
        *(float4*)(out_flat + base) = make_float4(fl[0], fl[1], fl[2], fl[3]);
    }

    const int rem = N - (ngroups << 2);
    if (tid0 < rem){
        const int p = (ngroups << 2) + tid0;
        const float x = coords[3LL*p+0];
        const float y = coords[3LL*p+1];
        const float z = coords[3LL*p+2];
        const int r = row_of(p, sp0, sp1, sp2, row_splits, n_rs);
        const int b0 = bin_of(x, mn0, w, nb0);
        const int b1 = bin_of(y, mn1, w, nb1);
        const int b2 = bin_of(z, mn2, w, nb2);
        out_assigned[p] = make_float4((float)r, (float)b0, (float)b1, (float)b2);
        const int flat = ((r * nb0 + b0) * nb1 + b1) * nb2 + b2;
        out_flat[p] = (float)flat;
    }
}

// ---- generic fallback (global atomics into counts region), kept for safety ----
__global__ void k_hist_glob(const float* __restrict__ coords,
                            const int* __restrict__ row_splits, int n_rs,
                            const int* __restrict__ nbins,
                            const float* __restrict__ bin_width,
                            const u32* __restrict__ mins,
                            int N, int* __restrict__ counts){
    const float w  = bin_width[0];
    const float mn0 = ord2f(mins[0]);
    const float mn1 = ord2f(mins[1]);
    const float mn2 = ord2f(mins[2]);
    const int nb0 = nbins[0], nb1 = nbins[1], nb2 = nbins[2];
    const int sp0 = (1 <= n_rs) ? row_splits[1] : 0x7FFFFFFF;
    const int sp1 = (2 <= n_rs) ? row_splits[2] : 0x7FFFFFFF;
    const int sp2 = (3 <= n_rs) ? row_splits[3] : 0x7FFFFFFF;
    const int stride = gridDim.x * blockDim.x;
    for (int p = blockIdx.x * blockDim.x + threadIdx.x; p < N; p += stride){
        const int r = row_of(p, sp0, sp1, sp2, row_splits, n_rs);
        const int b0 = bin_of(coords[3LL*p+0], mn0, w, nb0);
        const int b1 = bin_of(coords[3LL*p+1], mn1, w, nb1);
        const int b2 = bin_of(coords[3LL*p+2], mn2, w, nb2);
        atomicAdd(counts + ((r * nb0 + b0) * nb1 + b1) * nb2 + b2, 1);
    }
}
__global__ void k_convert(float* __restrict__ buf, int n){
    int i = blockIdx.x * blockDim.x + threadIdx.x;
    if (i < n){ int v = ((const int*)buf)[i]; buf[i] = (float)v; }
}

extern "C" void kernel_launch(void* const* d_in, const int* in_sizes, int n_in,
                              void* d_out, int out_size, void* d_ws, size_t ws_size,
                              hipStream_t stream){
    const float* coords    = (const float*)d_in[0];
    const int*  row_splits = (const int*)d_in[1];   // JAX x64 off: int32
    const float* bin_width = (const float*)d_in[2];
    const int*  nbins      = (const int*)d_in[3];   // int32
    const int N     = in_sizes[0] / 3;
    const int n_rs  = in_sizes[1] - 1;
    const int ndims = in_sizes[3];
    const long long total_bins = (long long)out_size - 5LL * N - ndims - 1;
    const int spatial = (int)(total_bins / n_rs);   // bins per event
    const int half = (spatial + 1) >> 1;

    float* out        = (float*)d_out;
    float* out_counts = out + 5LL * N;
    float* out_tail   = out_counts + total_bins;
    u32*   mins       = (u32*)d_ws;                 // 12 B (proven available)
    u32*   part       = (u32*)d_out;                // partials scratch in assigned region

    k_init<<<1, 64, 0, stream>>>(mins, out_tail, nbins, bin_width, ndims);

    const int ngroups = N >> 2;
    int gcnt = (ngroups + 255) / 256; if (gcnt > 2048) gcnt = 2048;
    k_min3<<<gcnt, 256, 0, stream>>>((const float4*)coords, ngroups, mins);

    // LDS path requires: half fits the 32000-counter LDS array, u16 can't
    // overflow (worst chunk = N/CPE+4 < 65536), partials fit assigned region.
    const long long part_bytes = (long long)n_rs * CPE * 2 * HWORDS * 4;
    const bool lds_ok = (half <= 2 * HWORDS) && (N / CPE + 8 < 65536) &&
                        (part_bytes <= 16LL * N) && (n_rs >= 1);

    if (lds_ok){
        k_hist_lds<<<n_rs * CPE, 1024, 0, stream>>>(coords, row_splits, nbins,
                                                    bin_width, mins, part,
                                                    spatial, half);
        int grd = (int)((total_bins + 255) / 256);
        k_hreduce<<<grd, 256, 0, stream>>>((const u16*)part, (int)total_bins,
                                           spatial, half, out_counts);
    } else {
        (void)hipMemsetAsync(out_counts, 0, (size_t)total_bins * sizeof(int), stream);
        k_hist_glob<<<gcnt, 256, 0, stream>>>(coords, row_splits, n_rs, nbins,
                                              bin_width, mins, N, (int*)out_counts);
        int gcv = (int)((total_bins + 255) / 256);
        k_convert<<<gcv, 256, 0, stream>>>(out_counts, (int)total_bins);
    }

    k_out<<<gcnt, 256, 0, stream>>>(coords, row_splits, n_rs, nbins, bin_width,
                                    mins, N, out);
}

// Round 7
// 575.832 us; speedup vs baseline: 1.4502x; 1.4502x over previous
//
#include <hip/hip_runtime.h>

typedef unsigned int u32;
typedef unsigned short u16;

#define FLT_BIG 3.402823466e+38f
#define CPE 128         // chunks per event; worst chunk <= ceil(N/CPE) = 62500 < 65536 -> u16-safe for ANY split layout
#define HWORDS 16000    // LDS u32 words = 32000 u16 counters (62.5 KB static)

// Order-preserving map: float -> u32 so unsigned atomicMin == float min.
__device__ __forceinline__ u32 f2ord(float f){
    u32 b = __float_as_uint(f);
    return (b & 0x80000000u) ? ~b : (b | 0x80000000u);
}
__device__ __forceinline__ float ord2f(u32 k){
    u32 b = (k & 0x80000000u) ? (k ^ 0x80000000u) : ~k;
    return __uint_as_float(b);
}

// NOTE: JAX x64 disabled -> "int64" inputs are int32 on device.
__global__ void k_init(u32* __restrict__ mins,
                       float* __restrict__ out_tail,
                       const int* __restrict__ nbins,
                       const float* __restrict__ bin_width,
                       int ndims){
    int t = threadIdx.x;
    if (t < 3) mins[t] = 0xFFFFFFFFu;
    if (t < ndims) out_tail[t] = (float)nbins[t];
    if (t == 0) out_tail[ndims] = bin_width[0];
}

// Per-dim min over [N,3] f32, read as groups of 3 float4 (= 4 points).
__global__ void k_min3(const float4* __restrict__ c4, int ngroups, u32* __restrict__ mins){
    float m0 = FLT_BIG, m1 = FLT_BIG, m2 = FLT_BIG;
    const int stride = gridDim.x * blockDim.x;
    for (int g = blockIdx.x * blockDim.x + threadIdx.x; g < ngroups; g += stride){
        const float4 v0 = c4[3*g+0];
        const float4 v1 = c4[3*g+1];
        const float4 v2 = c4[3*g+2];
        m0 = fminf(m0, fminf(v0.x, v0.w)); m1 = fminf(m1, v0.y); m2 = fminf(m2, v0.z);
        m1 = fminf(m1, fminf(v1.x, v1.w)); m2 = fminf(m2, v1.y); m0 = fminf(m0, v1.z);
        m2 = fminf(m2, fminf(v2.x, v2.w)); m0 = fminf(m0, v2.y); m1 = fminf(m1, v2.z);
    }
    #pragma unroll
    for (int off = 32; off > 0; off >>= 1){
        m0 = fminf(m0, __shfl_down(m0, off));
        m1 = fminf(m1, __shfl_down(m1, off));
        m2 = fminf(m2, __shfl_down(m2, off));
    }
    if ((threadIdx.x & 63) == 0){
        atomicMin(mins + 0, f2ord(m0));
        atomicMin(mins + 1, f2ord(m1));
        atomicMin(mins + 2, f2ord(m2));
    }
}

__device__ __forceinline__ int bin_of(float x, float mn, float w, int nb){
    float c = x - mn;
    int b = (int)floorf(c / w);
    b = b < 0 ? 0 : b;
    b = b > nb - 1 ? nb - 1 : b;
    return b;
}

__device__ __forceinline__ int row_of(int p, int sp0, int sp1, int sp2,
                                      const int* row_splits, int n_rs){
    int r = (p >= sp0) + (p >= sp1) + (p >= sp2);
    if (n_rs > 4){
        for (int k = 4; k < n_rs; ++k) r += (p >= row_splits[k]) ? 1 : 0;
    }
    return r;
}

// LDS-privatized histogram. One block per (event, chunk); the chunk lies
// entirely inside one event (row constant per block -> spatial bins only).
// Two passes over the chunk (spatial < half, then >= half); each point lands
// exactly one LDS atomic across the two passes. u16 packed 2-per-u32.
__global__ __launch_bounds__(1024)
void k_hist_lds(const float* __restrict__ coords,
                const int* __restrict__ row_splits,
                const int* __restrict__ nbins,
                const float* __restrict__ bin_width,
                const u32* __restrict__ mins,
                u32* __restrict__ part,      // [n_rs*CPE][2][HWORDS] u32
                int spatial, int half){
    __shared__ u32 hh[HWORDS];

    const float w  = bin_width[0];
    const float mn0 = ord2f(mins[0]);
    const float mn1 = ord2f(mins[1]);
    const float mn2 = ord2f(mins[2]);
    const int nb0 = nbins[0], nb1 = nbins[1], nb2 = nbins[2];

    const int e = blockIdx.x / CPE;
    const int i = blockIdx.x % CPE;
    const int lo = row_splits[e];
    const int hi = row_splits[e + 1];
    const long long len = (long long)hi - lo;
    const int start = lo + (int)((len * i) / CPE);
    const int end   = lo + (int)((len * (i + 1)) / CPE);

    int a4 = (start + 3) & ~3; if (a4 > end) a4 = end;
    int b4 = end & ~3;         if (b4 < a4) b4 = a4;
    const int tid = threadIdx.x;
    const float4* c4 = (const float4*)coords;

    for (int hp = 0; hp < 2; ++hp){
        for (int j = tid; j < HWORDS; j += 1024) hh[j] = 0;
        __syncthreads();
        const int F0 = hp ? half : 0;
        const int F1 = hp ? spatial : half;

        // scalar head + tail (at most 6 points)
        const int nh = a4 - start;
        const int nt = end - b4;
        if (tid < nh + nt){
            const int p = (tid < nh) ? (start + tid) : (b4 + (tid - nh));
            const int b0 = bin_of(coords[3LL*p+0], mn0, w, nb0);
            const int b1 = bin_of(coords[3LL*p+1], mn1, w, nb1);
            const int b2 = bin_of(coords[3LL*p+2], mn2, w, nb2);
            const int s = (b0 * nb1 + b1) * nb2 + b2;
            if (s >= F0 && s < F1){
                const int idx = s - F0;
                atomicAdd(&hh[idx >> 1], 1u << ((idx & 1) << 4));
            }
        }
        // vector body
        for (int g = (a4 >> 2) + tid; g < (b4 >> 2); g += 1024){
            const float4 v0 = c4[3*g+0];
            const float4 v1 = c4[3*g+1];
            const float4 v2 = c4[3*g+2];
            float px[4], py[4], pz[4];
            px[0]=v0.x; py[0]=v0.y; pz[0]=v0.z;
            px[1]=v0.w; py[1]=v1.x; pz[1]=v1.y;
            px[2]=v1.z; py[2]=v1.w; pz[2]=v2.x;
            px[3]=v2.y; py[3]=v2.z; pz[3]=v2.w;
            #pragma unroll
            for (int j = 0; j < 4; ++j){
                const int b0 = bin_of(px[j], mn0, w, nb0);
                const int b1 = bin_of(py[j], mn1, w, nb1);
                const int b2 = bin_of(pz[j], mn2, w, nb2);
                const int s = (b0 * nb1 + b1) * nb2 + b2;
                if (s >= F0 && s < F1){
                    const int idx = s - F0;
                    atomicAdd(&hh[idx >> 1], 1u << ((idx & 1) << 4));
                }
            }
        }
        __syncthreads();
        // flush partial (coalesced u32 stream)
        u32* dst = part + ((long long)(e * CPE + i) * 2 + hp) * HWORDS;
        for (int j = tid; j < HWORDS; j += 1024) dst[j] = hh[j];
        __syncthreads();   // protect hh before next pass's zeroing
    }
}

// counts_out[b] = (float) sum over CPE chunk-partials of b's event.
__global__ void k_hreduce(const u16* __restrict__ part, int total_bins,
                          int spatial, int half, float* __restrict__ counts_out){
    int b = blockIdx.x * blockDim.x + threadIdx.x;
    if (b >= total_bins) return;
    const int e = b / spatial;
    const int s = b % spatial;
    const int hp = (s >= half) ? 1 : 0;
    const int idx = s - hp * half;
    // each chunk owns 2*(2*HWORDS) u16 (= both halves)
    const u16* base = part + ((long long)(e * CPE) * 2 + hp) * (2 * HWORDS) + idx;
    int sum = 0;
    #pragma unroll 8
    for (int i = 0; i < CPE; ++i) sum += base[(long long)i * 2 * (2 * HWORDS)];
    counts_out[b] = (float)sum;
}

// Output pass: pure streaming, no atomics. Overwrites the partials scratch
// region (safe: k_hreduce already consumed it — stream-ordered).
__global__ void k_out(const float* __restrict__ coords,
                      const int* __restrict__ row_splits, int n_rs,
                      const int* __restrict__ nbins,
                      const float* __restrict__ bin_width,
                      const u32* __restrict__ mins,
                      int N,
                      float* __restrict__ out){
    const float w  = bin_width[0];
    const float mn0 = ord2f(mins[0]);
    const float mn1 = ord2f(mins[1]);
    const float mn2 = ord2f(mins[2]);
    const int nb0 = nbins[0], nb1 = nbins[1], nb2 = nbins[2];
    const int sp0 = (1 <= n_rs) ? row_splits[1] : 0x7FFFFFFF;
    const int sp1 = (2 <= n_rs) ? row_splits[2] : 0x7FFFFFFF;
    const int sp2 = (3 <= n_rs) ? row_splits[3] : 0x7FFFFFFF;

    float4* out_assigned = (float4*)out;                 // [N] x float4
    float*  out_flat     = out + 4LL * (long long)N;     // [N]
    const float4* c4 = (const float4*)coords;

    const int ngroups = N >> 2;
    const int stride = gridDim.x * blockDim.x;
    const int tid0 = blockIdx.x * blockDim.x + threadIdx.x;

    for (int g = tid0; g < ngroups; g += stride){
        const float4 v0 = c4[3*g+0];
        const float4 v1 = c4[3*g+1];
        const float4 v2 = c4[3*g+2];
        float px[4], py[4], pz[4];
        px[0]=v0.x; py[0]=v0.y; pz[0]=v0.z;
        px[1]=v0.w; py[1]=v1.x; pz[1]=v1.y;
        px[2]=v1.z; py[2]=v1.w; pz[2]=v2.x;
        px[3]=v2.y; py[3]=v2.z; pz[3]=v2.w;

        const int base = g << 2;
        float fl[4];
        #pragma unroll
        for (int j = 0; j < 4; ++j){
            const int p = base + j;
            const int r = row_of(p, sp0, sp1, sp2, row_splits, n_rs);
            const int b0 = bin_of(px[j], mn0, w, nb0);
            const int b1 = bin_of(py[j], mn1, w, nb1);
            const int b2 = bin_of(pz[j], mn2, w, nb2);
            out_assigned[p] = make_float4((float)r, (float)b0, (float)b1, (float)b2);
            const int flat = ((r * nb0 + b0) * nb1 + b1) * nb2 + b2;
            fl[j] = (float)flat;
        }
        *(float4*)(out_flat + base) = make_float4(fl[0], fl[1], fl[2], fl[3]);
    }

    const int rem = N - (ngroups << 2);
    if (tid0 < rem){
        const int p = (ngroups << 2) + tid0;
        const float x = coords[3LL*p+0];
        const float y = coords[3LL*p+1];
        const float z = coords[3LL*p+2];
        const int r = row_of(p, sp0, sp1, sp2, row_splits, n_rs);
        const int b0 = bin_of(x, mn0, w, nb0);
        const int b1 = bin_of(y, mn1, w, nb1);
        const int b2 = bin_of(z, mn2, w, nb2);
        out_assigned[p] = make_float4((float)r, (float)b0, (float)b1, (float)b2);
        const int flat = ((r * nb0 + b0) * nb1 + b1) * nb2 + b2;
        out_flat[p] = (float)flat;
    }
}

// ---- generic fallback (global atomics into counts region) ----
__global__ void k_hist_glob(const float* __restrict__ coords,
                            const int* __restrict__ row_splits, int n_rs,
                            const int* __restrict__ nbins,
                            const float* __restrict__ bin_width,
                            const u32* __restrict__ mins,
                            int N, int* __restrict__ counts){
    const float w  = bin_width[0];
    const float mn0 = ord2f(mins[0]);
    const float mn1 = ord2f(mins[1]);
    const float mn2 = ord2f(mins[2]);
    const int nb0 = nbins[0], nb1 = nbins[1], nb2 = nbins[2];
    const int sp0 = (1 <= n_rs) ? row_splits[1] : 0x7FFFFFFF;
    const int sp1 = (2 <= n_rs) ? row_splits[2] : 0x7FFFFFFF;
    const int sp2 = (3 <= n_rs) ? row_splits[3] : 0x7FFFFFFF;
    const int stride = gridDim.x * blockDim.x;
    for (int p = blockIdx.x * blockDim.x + threadIdx.x; p < N; p += stride){
        const int r = row_of(p, sp0, sp1, sp2, row_splits, n_rs);
        const int b0 = bin_of(coords[3LL*p+0], mn0, w, nb0);
        const int b1 = bin_of(coords[3LL*p+1], mn1, w, nb1);
        const int b2 = bin_of(coords[3LL*p+2], mn2, w, nb2);
        atomicAdd(counts + ((r * nb0 + b0) * nb1 + b1) * nb2 + b2, 1);
    }
}
__global__ void k_convert(float* __restrict__ buf, int n){
    int i = blockIdx.x * blockDim.x + threadIdx.x;
    if (i < n){ int v = ((const int*)buf)[i]; buf[i] = (float)v; }
}

extern "C" void kernel_launch(void* const* d_in, const int* in_sizes, int n_in,
                              void* d_out, int out_size, void* d_ws, size_t ws_size,
                              hipStream_t stream){
    const float* coords    = (const float*)d_in[0];
    const int*  row_splits = (const int*)d_in[1];   // JAX x64 off: int32
    const float* bin_width = (const float*)d_in[2];
    const int*  nbins      = (const int*)d_in[3];   // int32
    const int N     = in_sizes[0] / 3;
    const int n_rs  = in_sizes[1] - 1;
    const int ndims = in_sizes[3];
    const long long total_bins = (long long)out_size - 5LL * N - ndims - 1;
    const int spatial = (int)(total_bins / n_rs);   // bins per event
    const int half = (spatial + 1) >> 1;

    float* out        = (float*)d_out;
    float* out_counts = out + 5LL * N;
    float* out_tail   = out_counts + total_bins;
    u32*   mins       = (u32*)d_ws;                 // 12 B (proven available)
    u32*   part       = (u32*)d_out;                // partials scratch in assigned region

    k_init<<<1, 64, 0, stream>>>(mins, out_tail, nbins, bin_width, ndims);

    const int ngroups = N >> 2;
    int gcnt = (ngroups + 255) / 256; if (gcnt > 2048) gcnt = 2048;
    k_min3<<<gcnt, 256, 0, stream>>>((const float4*)coords, ngroups, mins);

    // LDS-path gate. Worst chunk over ANY split layout = ceil(N/CPE)+1;
    // CPE=128 keeps it < 65536 for N up to ~8.38M.
    const long long part_bytes = (long long)n_rs * CPE * 2 * HWORDS * 4;
    const bool lds_ok = (half <= 2 * HWORDS) &&
                        ((long long)N / CPE + 2 < 65536) &&
                        (part_bytes <= 16LL * N) &&
                        ((long long)n_rs * spatial == total_bins) && (n_rs >= 1);

    if (lds_ok){
        k_hist_lds<<<n_rs * CPE, 1024, 0, stream>>>(coords, row_splits, nbins,
                                                    bin_width, mins, part,
                                                    spatial, half);
        int grd = (int)((total_bins + 255) / 256);
        k_hreduce<<<grd, 256, 0, stream>>>((const u16*)part, (int)total_bins,
                                           spatial, half, out_counts);
    } else {
        (void)hipMemsetAsync(out_counts, 0, (size_t)total_bins * sizeof(int), stream);
        k_hist_glob<<<gcnt, 256, 0, stream>>>(coords, row_splits, n_rs, nbins,
                                              bin_width, mins, N, (int*)out_counts);
        int gcv = (int)((total_bins + 255) / 256);
        k_convert<<<gcv, 256, 0, stream>>>(out_counts, (int)total_bins);
    }

    k_out<<<gcnt, 256, 0, stream>>>(coords, row_splits, n_rs, nbins, bin_width,
                                    mins, N, out);
}